// Round 15
// baseline (1040.899 us; speedup 1.0000x reference)
//
#include <hip/hip_runtime.h>
#include <hip/hip_bf16.h>

// ---------------------------------------------------------------------------
// LSTM LM forward on MI355X — round 15 (round-14 design, K-half bug fixed).
// Fused persistent kernel (256 blocks x 512 thr): 32 L0 + 32 L1 + 192 decoder.
// L1's W1·h0 tail merged into the pacing phase (staged region holds
// h1(it-2) @0 | h0(it) @520; both MFMA groups per phase; P parity-double-
// buffered). Wave-private row ownership (4 gates x 4 j per wave). 2 barriers
// per step. Sentinel-polled write-once rings carry the h-chain (no flags);
// flags1 only gates the decoder, published every 4th step.
// FIX vs r14: W1·h0 MFMA reads LDS at c0 = 520 + kh*256 (was 520 for both
// K-half waves -> kh=1 multiplied wrong h0 half).
// ---------------------------------------------------------------------------

#define NVOC 32000
#define DIM  512
#define HID  512
#define SEQ  128
#define BAT  32
#define NB   64      // recurrence blocks (32 per layer)
#define NDEC 192     // decoder blocks
#define NTILE (32 * 250)
#define SLOT (BAT * HID)           // 16384 shorts per ring slot

typedef short s8v __attribute__((ext_vector_type(8)));
typedef short s4v __attribute__((ext_vector_type(4)));
typedef float f4v __attribute__((ext_vector_type(4)));
typedef unsigned long long u64;

__device__ __forceinline__ short f2bf(float f) {
    unsigned u = __builtin_bit_cast(unsigned, f);
    unsigned r = (u + 0x7fffu + ((u >> 16) & 1u)) >> 16;
    return (short)r;
}
__device__ __forceinline__ float bf2f(short s) {
    unsigned u = ((unsigned)(unsigned short)s) << 16;
    return __builtin_bit_cast(float, u);
}
__device__ __forceinline__ float sigm(float x) { return 1.f / (1.f + __expf(-x)); }
__device__ __forceinline__ float ftanh(float x) {
    float e = __expf(2.f * x);
    return 1.f - 2.f / (e + 1.f);
}

__device__ __forceinline__ f4v mf16(s8v a, s8v b, f4v c) {
    return __builtin_amdgcn_mfma_f32_16x16x32_bf16(a, b, c, 0, 0, 0);
}

// coherent (cross-XCD) loads/stores, bypassing L1+L2
__device__ __forceinline__ u64 cohload8(const short* p) {
    return __hip_atomic_load((const u64*)p, __ATOMIC_RELAXED,
                             __HIP_MEMORY_SCOPE_AGENT);
}
__device__ __forceinline__ void cohstore2(short* p, unsigned short v) {
    __hip_atomic_store((unsigned short*)p, v, __ATOMIC_RELAXED,
                       __HIP_MEMORY_SCOPE_AGENT);
}

// any halfword == 0xFFFF ? (has-zero-halfword test on ~v)
__device__ __forceinline__ bool hasSent(u64 v) {
    u64 n = ~v;
    return ((n - 0x0001000100010001ull) & ~n & 0x8000800080008000ull) != 0ull;
}

// 32-flag sleep-poll (decoder only)
__device__ __forceinline__ void poll32s(const unsigned* f, int l, unsigned tgt) {
    const unsigned* p = f + (l & 31);
    while (true) {
        unsigned v = __hip_atomic_load(p, __ATOMIC_RELAXED,
                                       __HIP_MEMORY_SCOPE_AGENT);
        if (__all((int)(v >= tgt))) break;
        __builtin_amdgcn_s_sleep(16);
    }
}

// ---------------- prep kernels ---------------------------------------------
__global__ __launch_bounds__(256) void prep_dec(const float* __restrict__ dw,
                                                short* __restrict__ dbf)
{
    int id = blockIdx.x * 256 + threadIdx.x;
    if (id >= (NVOC * DIM) / 4) return;
    int e = id * 4;
    float4 v = *(const float4*)(dw + e);
    s4v o; o[0] = f2bf(v.x); o[1] = f2bf(v.y); o[2] = f2bf(v.z); o[3] = f2bf(v.w);
    *(s4v*)(dbf + e) = o;
}

__global__ __launch_bounds__(256) void prep_w0(const float* __restrict__ W0,
                                               short* __restrict__ w0h,
                                               short* __restrict__ w0l)
{
    int id = blockIdx.x * 256 + threadIdx.x;
    if (id >= 2048 * 512) return;
    float v = W0[id];
    short h = f2bf(v);
    w0h[id] = h;
    w0l[id] = f2bf(v - bf2f(h));
}

__global__ __launch_bounds__(256) void embed_k(const int* __restrict__ toks,
                                               const float* __restrict__ emb,
                                               short* __restrict__ xemb)
{
    int id = blockIdx.x * 256 + threadIdx.x;
    if (id >= (SEQ * BAT * DIM) / 4) return;
    int e  = id * 4;
    int tb = e >> 9;
    int k4 = e & 511;
    int tok = toks[tb];
    float4 v = *(const float4*)(emb + (size_t)tok * DIM + k4);
    s4v o; o[0] = f2bf(v.x); o[1] = f2bf(v.y); o[2] = f2bf(v.z); o[3] = f2bf(v.w);
    *(s4v*)(xemb + e) = o;
}

// rings: ring0[129][SLOT] then ring1[129][SLOT]. slot0 = zeros (h(-1)),
// slots 1..128 = 0xFFFF sentinel. + zero flags.
__global__ __launch_bounds__(256) void init_k(short* __restrict__ hbuf,
                                              unsigned* __restrict__ bar)
{
    int id = blockIdx.x * 256 + threadIdx.x;   // u64 index
    const int ringU64 = 129 * SLOT / 4;
    if (id < 2 * ringU64) {
        int r = id % ringU64;
        u64 v = (r < SLOT / 4) ? 0ull : 0xFFFFFFFFFFFFFFFFull;
        ((u64*)hbuf)[id] = v;
    }
    if (id < 64) bar[id] = 0;
}

// ---------------- Gx0 GEMM: [4096,2048] = xemb @ (W0hi+W0lo)^T, fp32 out ----
__global__ __launch_bounds__(256) void gx_gemm(
    const short* __restrict__ A,
    const short* __restrict__ Bh,
    const short* __restrict__ Bl,
    float* __restrict__ out)
{
    const int nb = blockIdx.x & 15, mb = blockIdx.x >> 4;
    const int m0 = mb * 128, n0 = nb * 128;
    __shared__ short Alds[128][40];
    __shared__ short Bhl[128][40];
    __shared__ short Bll[128][40];
    const int tid = threadIdx.x, l = tid & 63, w = tid >> 6;
    const int wr = w >> 1, wc = w & 1;
    const int lr = l & 15, kg = l >> 4;

    f4v acc[4][4];
    #pragma unroll
    for (int mi = 0; mi < 4; ++mi)
        #pragma unroll
        for (int ni = 0; ni < 4; ++ni) {
            acc[mi][ni][0] = 0.f; acc[mi][ni][1] = 0.f;
            acc[mi][ni][2] = 0.f; acc[mi][ni][3] = 0.f;
        }

    for (int kt = 0; kt < 16; ++kt) {
        #pragma unroll
        for (int i = 0; i < 2; ++i) {
            int c = tid + i * 256;
            int row = c >> 2, q = (c & 3) << 3;
            *(s8v*)&Alds[row][q] = *(const s8v*)(A  + (size_t)(m0 + row) * 512 + kt * 32 + q);
            *(s8v*)&Bhl[row][q]  = *(const s8v*)(Bh + (size_t)(n0 + row) * 512 + kt * 32 + q);
            *(s8v*)&Bll[row][q]  = *(const s8v*)(Bl + (size_t)(n0 + row) * 512 + kt * 32 + q);
        }
        __syncthreads();
        s8v af[4], bhf[4], blf[4];
        #pragma unroll
        for (int i = 0; i < 4; ++i) {
            af[i]  = *(const s8v*)&Alds[wr * 64 + i * 16 + lr][kg * 8];
            bhf[i] = *(const s8v*)&Bhl[wc * 64 + i * 16 + lr][kg * 8];
            blf[i] = *(const s8v*)&Bll[wc * 64 + i * 16 + lr][kg * 8];
        }
        #pragma unroll
        for (int mi = 0; mi < 4; ++mi)
            #pragma unroll
            for (int ni = 0; ni < 4; ++ni) {
                acc[mi][ni] = mf16(af[mi], bhf[ni], acc[mi][ni]);
                acc[mi][ni] = mf16(af[mi], blf[ni], acc[mi][ni]);
            }
        __syncthreads();
    }

    #pragma unroll
    for (int mi = 0; mi < 4; ++mi)
        #pragma unroll
        for (int ni = 0; ni < 4; ++ni) {
            int n = n0 + wc * 64 + ni * 16 + lr;
            #pragma unroll
            for (int r = 0; r < 4; ++r) {
                int m = m0 + wr * 64 + mi * 16 + kg * 4 + r;
                out[(size_t)m * 2048 + n] = acc[mi][ni][r];
            }
        }
}

// ---------------- fused persistent recurrence + decoder ---------------------
__global__ __launch_bounds__(512, 1) void rnn_k(
    const float* __restrict__ W1f, const float* __restrict__ U0f,
    const float* __restrict__ U1f,
    const float* __restrict__ bias,
    const float* __restrict__ Gx,   // [4096][2048] fp32
    short* __restrict__ hbuf,       // ring0[129][SLOT] then ring1[129][SLOT]
    short* __restrict__ adec,       // [4096][512] bf16 (write-through)
    const short* __restrict__ dbf,  // dec_w bf16 [32000][512]
    const float* __restrict__ db,   // dec bias [32000]
    float* __restrict__ out,        // [4096][32000]
    unsigned* __restrict__ bar)     // flags1[32..63] (decoder gating only)
{
    const int tid = threadIdx.x;
    const int bx  = blockIdx.x;
    const int w2  = tid >> 6;
    const int l   = tid & 63;
    const int lr  = l & 15;
    const int kg  = l >> 4;

    __shared__ short Alds[32][1032];          // cols 0..511: primary, 520..1031: h0
    __shared__ float S[2][4][16][33];         // [kh][wq][gate*4+jq][batch]
    __shared__ float P[2][2][4][16][33];      // [parity][kh][wq][gate*4+jq][batch]
    __shared__ s8v AdT[4][132];
    __shared__ s8v BdT[4][132];

    if (bx >= NB) {
        // ================= decoder role =================
        const int d  = bx - NB;
        const int wm = w2 >> 2;
        const int wn = w2 & 3;
        const int drow = tid >> 2, dq = tid & 3;
        int lastmb = -1;
        for (int tile = d; tile < NTILE; tile += NDEC) {
            const int mb = tile / 250, nbt = tile - mb * 250;
            const int m0 = mb * 128, n0 = nbt * 128;
            if (mb != lastmb) {
                if (w2 == 0) poll32s(bar + 32, l, (unsigned)(4 * mb + 5));
                __syncthreads();
                lastmb = mb;
            }
            f4v acc[4][2];
            #pragma unroll
            for (int mi = 0; mi < 4; ++mi)
                #pragma unroll
                for (int ni = 0; ni < 2; ++ni) {
                    acc[mi][ni][0] = 0.f; acc[mi][ni][1] = 0.f;
                    acc[mi][ni][2] = 0.f; acc[mi][ni][3] = 0.f;
                }
            for (int kt = 0; kt < 16; ++kt) {
                AdT[dq][drow] = *(const s8v*)(adec + (size_t)(m0 + drow) * 512 + kt * 32 + dq * 8);
                BdT[dq][drow] = *(const s8v*)(dbf  + (size_t)(n0 + drow) * 512 + kt * 32 + dq * 8);
                __syncthreads();
                s8v af[4], bfr[2];
                #pragma unroll
                for (int i = 0; i < 4; ++i)
                    af[i] = AdT[kg][wm * 64 + i * 16 + lr];
                #pragma unroll
                for (int j = 0; j < 2; ++j)
                    bfr[j] = BdT[kg][wn * 32 + j * 16 + lr];
                #pragma unroll
                for (int mi = 0; mi < 4; ++mi)
                    #pragma unroll
                    for (int ni = 0; ni < 2; ++ni)
                        acc[mi][ni] = mf16(af[mi], bfr[ni], acc[mi][ni]);
                __syncthreads();
            }
            #pragma unroll
            for (int mi = 0; mi < 4; ++mi)
                #pragma unroll
                for (int ni = 0; ni < 2; ++ni) {
                    int n = n0 + wn * 32 + ni * 16 + lr;
                    float bb = db[n];
                    #pragma unroll
                    for (int r = 0; r < 4; ++r) {
                        int m = m0 + wm * 64 + mi * 16 + kg * 4 + r;
                        out[(size_t)m * NVOC + n] = acc[mi][ni][r] + bb;
                    }
                }
        }
        return;
    }

    // ================= recurrence roles =================
    const int bl    = bx;
    const int layer = bl >> 5;
    const int j0    = (bl & 31) * 16;
    const int wq    = w2 & 3;        // rowset (4 j's across all 4 gates)
    const int kh    = w2 >> 2;       // K-half

    // epilogue lane mapping: jq = l>>4, b = (l&15) + 16*kh
    const int jq = l >> 4;
    const int b  = (l & 15) + kh * 16;
    const int jj = j0 + wq * 4 + jq;
    const float bi = bias[jj];
    const float bf_ = bias[512 + jj];
    const float bg = bias[1024 + jj];
    const float bo = bias[1536 + jj];
    float cst = 0.f;

    short* ring0 = hbuf;                      // [129][SLOT]: slot t+1 = h0(t)
    short* ring1 = hbuf + 129 * SLOT;         // [129][SLOT]: slot t+1 = h1(t)

    // issue 8 coherent loads for a 32x512 slot
    auto issue8 = [&](const short* s, u64* va) {
        #pragma unroll
        for (int i = 0; i < 8; ++i) {
            int c = tid + i * 512;
            va[i] = cohload8(s + (c >> 7) * HID + (c & 127) * 4);
        }
    };
    // sentinel-retry + commit to Alds at column base c0
    auto commit8 = [&](const short* s, u64* va, int c0) {
        #pragma unroll
        for (int i = 0; i < 8; ++i) {
            int c = tid + i * 512;
            while (hasSent(va[i]))
                va[i] = cohload8(s + (c >> 7) * HID + (c & 127) * 4);
            *(u64*)&Alds[c >> 7][c0 + (c & 127) * 4] = va[i];
        }
    };
    // wave's 16 weight rows: grow = gate*512 + j0 + wq*4 + (lr&3), K-half kh
    const int grow = (lr >> 2) * 512 + j0 + wq * 4 + (lr & 3);
    auto loadw = [&](const float* M, s8v* WH, s8v* WL) {
        #pragma unroll
        for (int ks = 0; ks < 8; ++ks) {
            const float* src = M + (size_t)grow * 512 + kh * 256 + ks * 32 + kg * 8;
            float4 va = *(const float4*)src;
            float4 vb = *(const float4*)(src + 4);
            float vv[8] = {va.x, va.y, va.z, va.w, vb.x, vb.y, vb.z, vb.w};
            s8v hi, lo;
            #pragma unroll
            for (int e = 0; e < 8; ++e) {
                short h = f2bf(vv[e]);
                hi[e] = h; lo[e] = f2bf(vv[e] - bf2f(h));
            }
            WH[ks] = hi; WL[ks] = lo;
        }
    };
    // 8-ks hi/lo MFMA vs Alds region c0; partials -> dst[kh][wq]
    auto mfmaS = [&](const s8v* WH, const s8v* WL, int c0,
                     float (&dst)[2][4][16][33]) {
        f4v a0h = {0.f, 0.f, 0.f, 0.f};
        f4v a0l = a0h, a1h = a0h, a1l = a0h;
        #pragma unroll
        for (int ks = 0; ks < 8; ++ks) {
            const int k = c0 + ks * 32 + kg * 8;
            s8v a0 = *(const s8v*)&Alds[lr][k];
            s8v a1 = *(const s8v*)&Alds[16 + lr][k];
            a0h = mf16(a0, WH[ks], a0h);
            a0l = mf16(a0, WL[ks], a0l);
            a1h = mf16(a1, WH[ks], a1h);
            a1l = mf16(a1, WL[ks], a1l);
        }
        #pragma unroll
        for (int r = 0; r < 4; ++r) {
            dst[kh][wq][lr][kg * 4 + r]      = a0h[r] + a0l[r];
            dst[kh][wq][lr][16 + kg * 4 + r] = a1h[r] + a1l[r];
        }
    };

    if (layer == 0) {
        // ------ L0: h0(t) = act(U0·h0(t-1) + Gx(t)); 2 barriers, no flags ---
        s8v wh[8], wl[8];
        loadw(U0f, wh, wl);      // U0 K-half kh (staged full-width at c0=0)
        for (int it = 0; it < SEQ; ++it) {
            u64 va[8];
            issue8(ring0 + (size_t)it * SLOT, va);
            const float* gp = Gx + ((size_t)it * BAT + b) * 2048 + jj;
            float gx0 = gp[0], gx1 = gp[512], gx2 = gp[1024], gx3 = gp[1536];
            commit8(ring0 + (size_t)it * SLOT, va, 0);
            __syncthreads();
            mfmaS(wh, wl, kh * 256, S);
            __syncthreads();
            float gvi = S[0][wq][0 * 4 + jq][b] + S[1][wq][0 * 4 + jq][b] + gx0;
            float gvf = S[0][wq][1 * 4 + jq][b] + S[1][wq][1 * 4 + jq][b] + gx1;
            float gvg = S[0][wq][2 * 4 + jq][b] + S[1][wq][2 * 4 + jq][b] + gx2;
            float gvo = S[0][wq][3 * 4 + jq][b] + S[1][wq][3 * 4 + jq][b] + gx3;
            float gi = sigm(gvi + bi);
            float gf = sigm(gvf + bf_);
            float gg = ftanh(gvg + bg);
            float go = sigm(gvo + bo);
            cst = gf * cst + gi * gg;
            unsigned short hs = (unsigned short)f2bf(go * ftanh(cst));
            cohstore2(ring0 + (size_t)(it + 1) * SLOT + b * HID + jj, hs);
        }
    } else {
        // -- L1: h1(t-1) = act(U1·h1(t-2) + P[prev]); also compute P[next] ---
        s8v whU[8], wlU[8], whW[8], wlW[8];
        loadw(U1f, whU, wlU);
        loadw(W1f, whW, wlW);
        {   // prologue: P[1] = W1·h0(0)
            u64 va[8];
            issue8(ring0 + 1 * SLOT, va);
            commit8(ring0 + 1 * SLOT, va, 520);
            __syncthreads();
            mfmaS(whW, wlW, 520 + kh * 256, P[1]);    // FIX: + kh*256
            __syncthreads();
        }
        for (int it = 1; it <= SEQ; ++it) {
            const bool doH0 = (it < SEQ);
            u64 vh1[8], vh0[8];
            issue8(ring1 + (size_t)(it - 1) * SLOT, vh1);
            if (doH0) issue8(ring0 + (size_t)(it + 1) * SLOT, vh0);
            commit8(ring1 + (size_t)(it - 1) * SLOT, vh1, 0);
            if (doH0) commit8(ring0 + (size_t)(it + 1) * SLOT, vh0, 520);
            __syncthreads();
            mfmaS(whU, wlU, kh * 256, S);                       // U1·h1(it-2)
            if (doH0) mfmaS(whW, wlW, 520 + kh * 256,           // FIX: + kh*256
                            P[(it + 1) & 1]);                   // W1·h0(it)
            __syncthreads();
            const int par = it & 1;
            float gvi = S[0][wq][0 * 4 + jq][b] + S[1][wq][0 * 4 + jq][b]
                      + P[par][0][wq][0 * 4 + jq][b] + P[par][1][wq][0 * 4 + jq][b];
            float gvf = S[0][wq][1 * 4 + jq][b] + S[1][wq][1 * 4 + jq][b]
                      + P[par][0][wq][1 * 4 + jq][b] + P[par][1][wq][1 * 4 + jq][b];
            float gvg = S[0][wq][2 * 4 + jq][b] + S[1][wq][2 * 4 + jq][b]
                      + P[par][0][wq][2 * 4 + jq][b] + P[par][1][wq][2 * 4 + jq][b];
            float gvo = S[0][wq][3 * 4 + jq][b] + S[1][wq][3 * 4 + jq][b]
                      + P[par][0][wq][3 * 4 + jq][b] + P[par][1][wq][3 * 4 + jq][b];
            float gi = sigm(gvi + bi);
            float gf = sigm(gvf + bf_);
            float gg = ftanh(gvg + bg);
            float go = sigm(gvo + bo);
            cst = gf * cst + gi * gg;
            unsigned short hs = (unsigned short)f2bf(go * ftanh(cst));
            cohstore2(ring1 + (size_t)it * SLOT + b * HID + jj, hs);
            cohstore2(adec + ((size_t)(it - 1) * BAT + b) * HID + jj, hs);
            if ((it & 3) == 0 || it == SEQ) {
                asm volatile("s_waitcnt vmcnt(0)" ::: "memory");
                __syncthreads();
                if (tid == 0)
                    __hip_atomic_store(bar + 32 + (bl & 31), (unsigned)(it + 1),
                                       __ATOMIC_RELAXED, __HIP_MEMORY_SCOPE_AGENT);
            }
        }
    }
}

extern "C" void kernel_launch(void* const* d_in, const int* in_sizes, int n_in,
                              void* d_out, int out_size, void* d_ws, size_t ws_size,
                              hipStream_t stream)
{
    const int*   toks = (const int*)d_in[0];
    const float* emb  = (const float*)d_in[1];
    const float* W0   = (const float*)d_in[2];
    const float* W1   = (const float*)d_in[3];
    const float* U0   = (const float*)d_in[4];
    const float* U1   = (const float*)d_in[5];
    const float* bias = (const float*)d_in[6];
    const float* dw   = (const float*)d_in[7];
    const float* db   = (const float*)d_in[8];
    float* out = (float*)d_out;

    char* ws = (char*)d_ws;
    size_t off = 0;
    auto alloc = [&](size_t bytes) -> void* {
        void* p = ws + off;
        off += (bytes + 255) & ~(size_t)255;
        return p;
    };
    short*    dbf  = (short*)alloc((size_t)NVOC * DIM * 2);
    short*    xemb = (short*)alloc((size_t)SEQ * BAT * DIM * 2);
    short*    w0h  = (short*)alloc(2048ull * 512 * 2);
    short*    w0l  = (short*)alloc(2048ull * 512 * 2);
    float*    Gx   = (float*)alloc((size_t)SEQ * BAT * 2048 * 4);
    short*    hbuf = (short*)alloc(2ull * 129 * SLOT * 2);
    short*    adec = (short*)alloc((size_t)SEQ * BAT * HID * 2);
    unsigned* bar  = (unsigned*)alloc(256);

    prep_dec<<<(NVOC * DIM / 4 + 255) / 256, 256, 0, stream>>>(dw, dbf);
    prep_w0 <<<(2048 * 512 + 255) / 256, 256, 0, stream>>>(W0, w0h, w0l);
    embed_k <<<(SEQ * BAT * DIM / 4 + 255) / 256, 256, 0, stream>>>(toks, emb, xemb);
    {
        int ringU64 = 2 * 129 * SLOT / 4;
        init_k<<<(ringU64 + 255) / 256, 256, 0, stream>>>(hbuf, bar);
    }

    gx_gemm<<<32 * 16, 256, 0, stream>>>(xemb, w0h, w0l, Gx);

    rnn_k<<<NB + NDEC, 512, 0, stream>>>(W1, U0, U1, bias, Gx, hbuf, adec,
                                         dbf, db, out, bar);
}

// Round 16
// 934.499 us; speedup vs baseline: 1.1139x; 1.1139x over previous
//
#include <hip/hip_runtime.h>
#include <hip/hip_bf16.h>

// ---------------------------------------------------------------------------
// LSTM LM forward on MI355X — round 16.
// Fused persistent kernel (256 blocks x 512 thr): 32 L0 + 32 L1 + 192 decoder.
// = round 15 (merged W1·h0 tail, P parity-double-buffered, 2 barriers/step,
// sentinel write-once rings) BUT with the r13 epilogue lane mapping
// (eb=tid>>4, ej=tid&15 -> adjacent lanes vary j): h-ring/adec stores and Gx
// loads are 16-lane contiguous again (r15's kh-split mapping scattered them).
// ---------------------------------------------------------------------------

#define NVOC 32000
#define DIM  512
#define HID  512
#define SEQ  128
#define BAT  32
#define NB   64      // recurrence blocks (32 per layer)
#define NDEC 192     // decoder blocks
#define NTILE (32 * 250)
#define SLOT (BAT * HID)           // 16384 shorts per ring slot

typedef short s8v __attribute__((ext_vector_type(8)));
typedef short s4v __attribute__((ext_vector_type(4)));
typedef float f4v __attribute__((ext_vector_type(4)));
typedef unsigned long long u64;

__device__ __forceinline__ short f2bf(float f) {
    unsigned u = __builtin_bit_cast(unsigned, f);
    unsigned r = (u + 0x7fffu + ((u >> 16) & 1u)) >> 16;
    return (short)r;
}
__device__ __forceinline__ float bf2f(short s) {
    unsigned u = ((unsigned)(unsigned short)s) << 16;
    return __builtin_bit_cast(float, u);
}
__device__ __forceinline__ float sigm(float x) { return 1.f / (1.f + __expf(-x)); }
__device__ __forceinline__ float ftanh(float x) {
    float e = __expf(2.f * x);
    return 1.f - 2.f / (e + 1.f);
}

__device__ __forceinline__ f4v mf16(s8v a, s8v b, f4v c) {
    return __builtin_amdgcn_mfma_f32_16x16x32_bf16(a, b, c, 0, 0, 0);
}

// coherent (cross-XCD) loads/stores, bypassing L1+L2
__device__ __forceinline__ u64 cohload8(const short* p) {
    return __hip_atomic_load((const u64*)p, __ATOMIC_RELAXED,
                             __HIP_MEMORY_SCOPE_AGENT);
}
__device__ __forceinline__ void cohstore2(short* p, unsigned short v) {
    __hip_atomic_store((unsigned short*)p, v, __ATOMIC_RELAXED,
                       __HIP_MEMORY_SCOPE_AGENT);
}

// any halfword == 0xFFFF ? (has-zero-halfword test on ~v)
__device__ __forceinline__ bool hasSent(u64 v) {
    u64 n = ~v;
    return ((n - 0x0001000100010001ull) & ~n & 0x8000800080008000ull) != 0ull;
}

// 32-flag sleep-poll (decoder only)
__device__ __forceinline__ void poll32s(const unsigned* f, int l, unsigned tgt) {
    const unsigned* p = f + (l & 31);
    while (true) {
        unsigned v = __hip_atomic_load(p, __ATOMIC_RELAXED,
                                       __HIP_MEMORY_SCOPE_AGENT);
        if (__all((int)(v >= tgt))) break;
        __builtin_amdgcn_s_sleep(16);
    }
}

// ---------------- prep kernels ---------------------------------------------
__global__ __launch_bounds__(256) void prep_dec(const float* __restrict__ dw,
                                                short* __restrict__ dbf)
{
    int id = blockIdx.x * 256 + threadIdx.x;
    if (id >= (NVOC * DIM) / 4) return;
    int e = id * 4;
    float4 v = *(const float4*)(dw + e);
    s4v o; o[0] = f2bf(v.x); o[1] = f2bf(v.y); o[2] = f2bf(v.z); o[3] = f2bf(v.w);
    *(s4v*)(dbf + e) = o;
}

__global__ __launch_bounds__(256) void prep_w0(const float* __restrict__ W0,
                                               short* __restrict__ w0h,
                                               short* __restrict__ w0l)
{
    int id = blockIdx.x * 256 + threadIdx.x;
    if (id >= 2048 * 512) return;
    float v = W0[id];
    short h = f2bf(v);
    w0h[id] = h;
    w0l[id] = f2bf(v - bf2f(h));
}

__global__ __launch_bounds__(256) void embed_k(const int* __restrict__ toks,
                                               const float* __restrict__ emb,
                                               short* __restrict__ xemb)
{
    int id = blockIdx.x * 256 + threadIdx.x;
    if (id >= (SEQ * BAT * DIM) / 4) return;
    int e  = id * 4;
    int tb = e >> 9;
    int k4 = e & 511;
    int tok = toks[tb];
    float4 v = *(const float4*)(emb + (size_t)tok * DIM + k4);
    s4v o; o[0] = f2bf(v.x); o[1] = f2bf(v.y); o[2] = f2bf(v.z); o[3] = f2bf(v.w);
    *(s4v*)(xemb + e) = o;
}

// rings: ring0[129][SLOT] then ring1[129][SLOT]. slot0 = zeros (h(-1)),
// slots 1..128 = 0xFFFF sentinel. + zero flags.
__global__ __launch_bounds__(256) void init_k(short* __restrict__ hbuf,
                                              unsigned* __restrict__ bar)
{
    int id = blockIdx.x * 256 + threadIdx.x;   // u64 index
    const int ringU64 = 129 * SLOT / 4;
    if (id < 2 * ringU64) {
        int r = id % ringU64;
        u64 v = (r < SLOT / 4) ? 0ull : 0xFFFFFFFFFFFFFFFFull;
        ((u64*)hbuf)[id] = v;
    }
    if (id < 64) bar[id] = 0;
}

// ---------------- Gx0 GEMM: [4096,2048] = xemb @ (W0hi+W0lo)^T, fp32 out ----
__global__ __launch_bounds__(256) void gx_gemm(
    const short* __restrict__ A,
    const short* __restrict__ Bh,
    const short* __restrict__ Bl,
    float* __restrict__ out)
{
    const int nb = blockIdx.x & 15, mb = blockIdx.x >> 4;
    const int m0 = mb * 128, n0 = nb * 128;
    __shared__ short Alds[128][40];
    __shared__ short Bhl[128][40];
    __shared__ short Bll[128][40];
    const int tid = threadIdx.x, l = tid & 63, w = tid >> 6;
    const int wr = w >> 1, wc = w & 1;
    const int lr = l & 15, kg = l >> 4;

    f4v acc[4][4];
    #pragma unroll
    for (int mi = 0; mi < 4; ++mi)
        #pragma unroll
        for (int ni = 0; ni < 4; ++ni) {
            acc[mi][ni][0] = 0.f; acc[mi][ni][1] = 0.f;
            acc[mi][ni][2] = 0.f; acc[mi][ni][3] = 0.f;
        }

    for (int kt = 0; kt < 16; ++kt) {
        #pragma unroll
        for (int i = 0; i < 2; ++i) {
            int c = tid + i * 256;
            int row = c >> 2, q = (c & 3) << 3;
            *(s8v*)&Alds[row][q] = *(const s8v*)(A  + (size_t)(m0 + row) * 512 + kt * 32 + q);
            *(s8v*)&Bhl[row][q]  = *(const s8v*)(Bh + (size_t)(n0 + row) * 512 + kt * 32 + q);
            *(s8v*)&Bll[row][q]  = *(const s8v*)(Bl + (size_t)(n0 + row) * 512 + kt * 32 + q);
        }
        __syncthreads();
        s8v af[4], bhf[4], blf[4];
        #pragma unroll
        for (int i = 0; i < 4; ++i) {
            af[i]  = *(const s8v*)&Alds[wr * 64 + i * 16 + lr][kg * 8];
            bhf[i] = *(const s8v*)&Bhl[wc * 64 + i * 16 + lr][kg * 8];
            blf[i] = *(const s8v*)&Bll[wc * 64 + i * 16 + lr][kg * 8];
        }
        #pragma unroll
        for (int mi = 0; mi < 4; ++mi)
            #pragma unroll
            for (int ni = 0; ni < 4; ++ni) {
                acc[mi][ni] = mf16(af[mi], bhf[ni], acc[mi][ni]);
                acc[mi][ni] = mf16(af[mi], blf[ni], acc[mi][ni]);
            }
        __syncthreads();
    }

    #pragma unroll
    for (int mi = 0; mi < 4; ++mi)
        #pragma unroll
        for (int ni = 0; ni < 4; ++ni) {
            int n = n0 + wc * 64 + ni * 16 + lr;
            #pragma unroll
            for (int r = 0; r < 4; ++r) {
                int m = m0 + wr * 64 + mi * 16 + kg * 4 + r;
                out[(size_t)m * 2048 + n] = acc[mi][ni][r];
            }
        }
}

// ---------------- fused persistent recurrence + decoder ---------------------
__global__ __launch_bounds__(512, 1) void rnn_k(
    const float* __restrict__ W1f, const float* __restrict__ U0f,
    const float* __restrict__ U1f,
    const float* __restrict__ bias,
    const float* __restrict__ Gx,   // [4096][2048] fp32
    short* __restrict__ hbuf,       // ring0[129][SLOT] then ring1[129][SLOT]
    short* __restrict__ adec,       // [4096][512] bf16 (write-through)
    const short* __restrict__ dbf,  // dec_w bf16 [32000][512]
    const float* __restrict__ db,   // dec bias [32000]
    float* __restrict__ out,        // [4096][32000]
    unsigned* __restrict__ bar)     // flags1[32..63] (decoder gating only)
{
    const int tid = threadIdx.x;
    const int bx  = blockIdx.x;
    const int w2  = tid >> 6;
    const int l   = tid & 63;
    const int lr  = l & 15;
    const int kg  = l >> 4;

    __shared__ short Alds[32][1032];          // cols 0..511: primary, 520..1031: h0
    __shared__ float S[2][4][16][33];         // [kh][wq][gate*4+jq][batch]
    __shared__ float P[2][2][4][16][33];      // [parity][kh][wq][gate*4+jq][batch]
    __shared__ s8v AdT[4][132];
    __shared__ s8v BdT[4][132];

    if (bx >= NB) {
        // ================= decoder role =================
        const int d  = bx - NB;
        const int wm = w2 >> 2;
        const int wn = w2 & 3;
        const int drow = tid >> 2, dq = tid & 3;
        int lastmb = -1;
        for (int tile = d; tile < NTILE; tile += NDEC) {
            const int mb = tile / 250, nbt = tile - mb * 250;
            const int m0 = mb * 128, n0 = nbt * 128;
            if (mb != lastmb) {
                if (w2 == 0) poll32s(bar + 32, l, (unsigned)(4 * mb + 5));
                __syncthreads();
                lastmb = mb;
            }
            f4v acc[4][2];
            #pragma unroll
            for (int mi = 0; mi < 4; ++mi)
                #pragma unroll
                for (int ni = 0; ni < 2; ++ni) {
                    acc[mi][ni][0] = 0.f; acc[mi][ni][1] = 0.f;
                    acc[mi][ni][2] = 0.f; acc[mi][ni][3] = 0.f;
                }
            for (int kt = 0; kt < 16; ++kt) {
                AdT[dq][drow] = *(const s8v*)(adec + (size_t)(m0 + drow) * 512 + kt * 32 + dq * 8);
                BdT[dq][drow] = *(const s8v*)(dbf  + (size_t)(n0 + drow) * 512 + kt * 32 + dq * 8);
                __syncthreads();
                s8v af[4], bfr[2];
                #pragma unroll
                for (int i = 0; i < 4; ++i)
                    af[i] = AdT[kg][wm * 64 + i * 16 + lr];
                #pragma unroll
                for (int j = 0; j < 2; ++j)
                    bfr[j] = BdT[kg][wn * 32 + j * 16 + lr];
                #pragma unroll
                for (int mi = 0; mi < 4; ++mi)
                    #pragma unroll
                    for (int ni = 0; ni < 2; ++ni)
                        acc[mi][ni] = mf16(af[mi], bfr[ni], acc[mi][ni]);
                __syncthreads();
            }
            #pragma unroll
            for (int mi = 0; mi < 4; ++mi)
                #pragma unroll
                for (int ni = 0; ni < 2; ++ni) {
                    int n = n0 + wn * 32 + ni * 16 + lr;
                    float bb = db[n];
                    #pragma unroll
                    for (int r = 0; r < 4; ++r) {
                        int m = m0 + wm * 64 + mi * 16 + kg * 4 + r;
                        out[(size_t)m * NVOC + n] = acc[mi][ni][r] + bb;
                    }
                }
        }
        return;
    }

    // ================= recurrence roles =================
    const int bl    = bx;
    const int layer = bl >> 5;
    const int j0    = (bl & 31) * 16;
    const int wq    = w2 & 3;        // rowset (4 j's across all 4 gates)
    const int kh    = w2 >> 2;       // K-half

    // epilogue lane mapping (r13 style): adjacent lanes vary j -> coalesced
    const int eb  = tid >> 4;        // batch 0..31
    const int ej  = tid & 15;        // j within block 0..15
    const int wqE = ej >> 2;         // which wave's S slab
    const int jqE = ej & 3;
    const int jj  = j0 + ej;
    const float bi = bias[jj];
    const float bf_ = bias[512 + jj];
    const float bg = bias[1024 + jj];
    const float bo = bias[1536 + jj];
    float cst = 0.f;

    short* ring0 = hbuf;                      // [129][SLOT]: slot t+1 = h0(t)
    short* ring1 = hbuf + 129 * SLOT;         // [129][SLOT]: slot t+1 = h1(t)

    // issue 8 coherent loads for a 32x512 slot
    auto issue8 = [&](const short* s, u64* va) {
        #pragma unroll
        for (int i = 0; i < 8; ++i) {
            int c = tid + i * 512;
            va[i] = cohload8(s + (c >> 7) * HID + (c & 127) * 4);
        }
    };
    // sentinel-retry + commit to Alds at column base c0
    auto commit8 = [&](const short* s, u64* va, int c0) {
        #pragma unroll
        for (int i = 0; i < 8; ++i) {
            int c = tid + i * 512;
            while (hasSent(va[i]))
                va[i] = cohload8(s + (c >> 7) * HID + (c & 127) * 4);
            *(u64*)&Alds[c >> 7][c0 + (c & 127) * 4] = va[i];
        }
    };
    // wave's 16 weight rows: grow = gate*512 + j0 + wq*4 + (lr&3), K-half kh
    const int grow = (lr >> 2) * 512 + j0 + wq * 4 + (lr & 3);
    auto loadw = [&](const float* M, s8v* WH, s8v* WL) {
        #pragma unroll
        for (int ks = 0; ks < 8; ++ks) {
            const float* src = M + (size_t)grow * 512 + kh * 256 + ks * 32 + kg * 8;
            float4 va = *(const float4*)src;
            float4 vb = *(const float4*)(src + 4);
            float vv[8] = {va.x, va.y, va.z, va.w, vb.x, vb.y, vb.z, vb.w};
            s8v hi, lo;
            #pragma unroll
            for (int e = 0; e < 8; ++e) {
                short h = f2bf(vv[e]);
                hi[e] = h; lo[e] = f2bf(vv[e] - bf2f(h));
            }
            WH[ks] = hi; WL[ks] = lo;
        }
    };
    // 8-ks hi/lo MFMA vs Alds region c0; partials -> dst[kh][wq]
    auto mfmaS = [&](const s8v* WH, const s8v* WL, int c0,
                     float (&dst)[2][4][16][33]) {
        f4v a0h = {0.f, 0.f, 0.f, 0.f};
        f4v a0l = a0h, a1h = a0h, a1l = a0h;
        #pragma unroll
        for (int ks = 0; ks < 8; ++ks) {
            const int k = c0 + ks * 32 + kg * 8;
            s8v a0 = *(const s8v*)&Alds[lr][k];
            s8v a1 = *(const s8v*)&Alds[16 + lr][k];
            a0h = mf16(a0, WH[ks], a0h);
            a0l = mf16(a0, WL[ks], a0l);
            a1h = mf16(a1, WH[ks], a1h);
            a1l = mf16(a1, WL[ks], a1l);
        }
        #pragma unroll
        for (int r = 0; r < 4; ++r) {
            dst[kh][wq][lr][kg * 4 + r]      = a0h[r] + a0l[r];
            dst[kh][wq][lr][16 + kg * 4 + r] = a1h[r] + a1l[r];
        }
    };

    if (layer == 0) {
        // ------ L0: h0(t) = act(U0·h0(t-1) + Gx(t)); 2 barriers, no flags ---
        s8v wh[8], wl[8];
        loadw(U0f, wh, wl);
        for (int it = 0; it < SEQ; ++it) {
            u64 va[8];
            issue8(ring0 + (size_t)it * SLOT, va);
            const float* gp = Gx + ((size_t)it * BAT + eb) * 2048 + jj;
            float gx0 = gp[0], gx1 = gp[512], gx2 = gp[1024], gx3 = gp[1536];
            commit8(ring0 + (size_t)it * SLOT, va, 0);
            __syncthreads();
            mfmaS(wh, wl, kh * 256, S);
            __syncthreads();
            float gvi = S[0][wqE][0 * 4 + jqE][eb] + S[1][wqE][0 * 4 + jqE][eb] + gx0;
            float gvf = S[0][wqE][1 * 4 + jqE][eb] + S[1][wqE][1 * 4 + jqE][eb] + gx1;
            float gvg = S[0][wqE][2 * 4 + jqE][eb] + S[1][wqE][2 * 4 + jqE][eb] + gx2;
            float gvo = S[0][wqE][3 * 4 + jqE][eb] + S[1][wqE][3 * 4 + jqE][eb] + gx3;
            float gi = sigm(gvi + bi);
            float gf = sigm(gvf + bf_);
            float gg = ftanh(gvg + bg);
            float go = sigm(gvo + bo);
            cst = gf * cst + gi * gg;
            unsigned short hs = (unsigned short)f2bf(go * ftanh(cst));
            cohstore2(ring0 + (size_t)(it + 1) * SLOT + eb * HID + jj, hs);
        }
    } else {
        // -- L1: h1(t-1) = act(U1·h1(t-2) + P[prev]); also compute P[next] ---
        s8v whU[8], wlU[8], whW[8], wlW[8];
        loadw(U1f, whU, wlU);
        loadw(W1f, whW, wlW);
        {   // prologue: P[1] = W1·h0(0)
            u64 va[8];
            issue8(ring0 + 1 * SLOT, va);
            commit8(ring0 + 1 * SLOT, va, 520);
            __syncthreads();
            mfmaS(whW, wlW, 520 + kh * 256, P[1]);
            __syncthreads();
        }
        for (int it = 1; it <= SEQ; ++it) {
            const bool doH0 = (it < SEQ);
            u64 vh1[8], vh0[8];
            issue8(ring1 + (size_t)(it - 1) * SLOT, vh1);
            if (doH0) issue8(ring0 + (size_t)(it + 1) * SLOT, vh0);
            commit8(ring1 + (size_t)(it - 1) * SLOT, vh1, 0);
            if (doH0) commit8(ring0 + (size_t)(it + 1) * SLOT, vh0, 520);
            __syncthreads();
            mfmaS(whU, wlU, kh * 256, S);                       // U1·h1(it-2)
            if (doH0) mfmaS(whW, wlW, 520 + kh * 256,
                            P[(it + 1) & 1]);                   // W1·h0(it)
            __syncthreads();
            const int par = it & 1;
            float gvi = S[0][wqE][0 * 4 + jqE][eb] + S[1][wqE][0 * 4 + jqE][eb]
                      + P[par][0][wqE][0 * 4 + jqE][eb] + P[par][1][wqE][0 * 4 + jqE][eb];
            float gvf = S[0][wqE][1 * 4 + jqE][eb] + S[1][wqE][1 * 4 + jqE][eb]
                      + P[par][0][wqE][1 * 4 + jqE][eb] + P[par][1][wqE][1 * 4 + jqE][eb];
            float gvg = S[0][wqE][2 * 4 + jqE][eb] + S[1][wqE][2 * 4 + jqE][eb]
                      + P[par][0][wqE][2 * 4 + jqE][eb] + P[par][1][wqE][2 * 4 + jqE][eb];
            float gvo = S[0][wqE][3 * 4 + jqE][eb] + S[1][wqE][3 * 4 + jqE][eb]
                      + P[par][0][wqE][3 * 4 + jqE][eb] + P[par][1][wqE][3 * 4 + jqE][eb];
            float gi = sigm(gvi + bi);
            float gf = sigm(gvf + bf_);
            float gg = ftanh(gvg + bg);
            float go = sigm(gvo + bo);
            cst = gf * cst + gi * gg;
            unsigned short hs = (unsigned short)f2bf(go * ftanh(cst));
            cohstore2(ring1 + (size_t)it * SLOT + eb * HID + jj, hs);
            cohstore2(adec + ((size_t)(it - 1) * BAT + eb) * HID + jj, hs);
            if ((it & 3) == 0 || it == SEQ) {
                asm volatile("s_waitcnt vmcnt(0)" ::: "memory");
                __syncthreads();
                if (tid == 0)
                    __hip_atomic_store(bar + 32 + (bl & 31), (unsigned)(it + 1),
                                       __ATOMIC_RELAXED, __HIP_MEMORY_SCOPE_AGENT);
            }
        }
    }
}

extern "C" void kernel_launch(void* const* d_in, const int* in_sizes, int n_in,
                              void* d_out, int out_size, void* d_ws, size_t ws_size,
                              hipStream_t stream)
{
    const int*   toks = (const int*)d_in[0];
    const float* emb  = (const float*)d_in[1];
    const float* W0   = (const float*)d_in[2];
    const float* W1   = (const float*)d_in[3];
    const float* U0   = (const float*)d_in[4];
    const float* U1   = (const float*)d_in[5];
    const float* bias = (const float*)d_in[6];
    const float* dw   = (const float*)d_in[7];
    const float* db   = (const float*)d_in[8];
    float* out = (float*)d_out;

    char* ws = (char*)d_ws;
    size_t off = 0;
    auto alloc = [&](size_t bytes) -> void* {
        void* p = ws + off;
        off += (bytes + 255) & ~(size_t)255;
        return p;
    };
    short*    dbf  = (short*)alloc((size_t)NVOC * DIM * 2);
    short*    xemb = (short*)alloc((size_t)SEQ * BAT * DIM * 2);
    short*    w0h  = (short*)alloc(2048ull * 512 * 2);
    short*    w0l  = (short*)alloc(2048ull * 512 * 2);
    float*    Gx   = (float*)alloc((size_t)SEQ * BAT * 2048 * 4);
    short*    hbuf = (short*)alloc(2ull * 129 * SLOT * 2);
    short*    adec = (short*)alloc((size_t)SEQ * BAT * HID * 2);
    unsigned* bar  = (unsigned*)alloc(256);

    prep_dec<<<(NVOC * DIM / 4 + 255) / 256, 256, 0, stream>>>(dw, dbf);
    prep_w0 <<<(2048 * 512 + 255) / 256, 256, 0, stream>>>(W0, w0h, w0l);
    embed_k <<<(SEQ * BAT * DIM / 4 + 255) / 256, 256, 0, stream>>>(toks, emb, xemb);
    {
        int ringU64 = 2 * 129 * SLOT / 4;
        init_k<<<(ringU64 + 255) / 256, 256, 0, stream>>>(hbuf, bar);
    }

    gx_gemm<<<32 * 16, 256, 0, stream>>>(xemb, w0h, w0l, Gx);

    rnn_k<<<NB + NDEC, 512, 0, stream>>>(W1, U0, U1, bias, Gx, hbuf, adec,
                                         dbf, db, out, bar);
}

// Round 17
// 695.595 us; speedup vs baseline: 1.4964x; 1.3435x over previous
//
#include <hip/hip_runtime.h>
#include <hip/hip_bf16.h>

// ---------------------------------------------------------------------------
// LSTM LM forward on MI355X — round 17 (r13 base + packed 4B h-stores,
// WAR-race barrier, merged prep launch).
// Fused persistent kernel (256 blocks x 512 thr): 32 L0 + 32 L1 + 192 decoder.
// Sentinel-polled write-once rings (129 slots) carry the h-chain (bf16 0xFFFF
// NaN sentinel); flags1 only gates the decoder (published every 4th step).
// L1 split into pacing phase (U1·h1 + epilogue) and tail (W1·h0 -> pbuf).
// ---------------------------------------------------------------------------

#define NVOC 32000
#define DIM  512
#define HID  512
#define SEQ  128
#define BAT  32
#define NB   64      // recurrence blocks (32 per layer)
#define NDEC 192     // decoder blocks
#define NTILE (32 * 250)
#define SLOT (BAT * HID)           // 16384 shorts per ring slot

typedef short s8v __attribute__((ext_vector_type(8)));
typedef short s4v __attribute__((ext_vector_type(4)));
typedef float f4v __attribute__((ext_vector_type(4)));
typedef unsigned long long u64;

__device__ __forceinline__ short f2bf(float f) {
    unsigned u = __builtin_bit_cast(unsigned, f);
    unsigned r = (u + 0x7fffu + ((u >> 16) & 1u)) >> 16;
    return (short)r;
}
__device__ __forceinline__ float bf2f(short s) {
    unsigned u = ((unsigned)(unsigned short)s) << 16;
    return __builtin_bit_cast(float, u);
}
__device__ __forceinline__ float sigm(float x) { return 1.f / (1.f + __expf(-x)); }
__device__ __forceinline__ float ftanh(float x) {
    float e = __expf(2.f * x);
    return 1.f - 2.f / (e + 1.f);
}

__device__ __forceinline__ f4v mf16(s8v a, s8v b, f4v c) {
    return __builtin_amdgcn_mfma_f32_16x16x32_bf16(a, b, c, 0, 0, 0);
}

// coherent (cross-XCD) loads/stores, bypassing L1+L2
__device__ __forceinline__ u64 cohload8(const short* p) {
    return __hip_atomic_load((const u64*)p, __ATOMIC_RELAXED,
                             __HIP_MEMORY_SCOPE_AGENT);
}
__device__ __forceinline__ void cohstore4(short* p, unsigned v) {
    __hip_atomic_store((unsigned*)p, v, __ATOMIC_RELAXED,
                       __HIP_MEMORY_SCOPE_AGENT);
}

// any halfword == 0xFFFF ? (has-zero-halfword test on ~v)
__device__ __forceinline__ bool hasSent(u64 v) {
    u64 n = ~v;
    return ((n - 0x0001000100010001ull) & ~n & 0x8000800080008000ull) != 0ull;
}

// 32-flag sleep-poll (decoder only)
__device__ __forceinline__ void poll32s(const unsigned* f, int l, unsigned tgt) {
    const unsigned* p = f + (l & 31);
    while (true) {
        unsigned v = __hip_atomic_load(p, __ATOMIC_RELAXED,
                                       __HIP_MEMORY_SCOPE_AGENT);
        if (__all((int)(v >= tgt))) break;
        __builtin_amdgcn_s_sleep(16);
    }
}

// ---------------- merged prep kernel ----------------------------------------
// blocks [0,16000): dec_w fp32->bf16 (NVOC*DIM/4 x4 elems)
// blocks [16000,20096): W0 split hi/lo (2048*512)
// blocks [20096,22144): embed gather -> xemb (SEQ*BAT*DIM/4 x4)
// blocks [22144,26272): ring init (sentinels) + flags
__global__ __launch_bounds__(256) void prep_all(
    const float* __restrict__ dw, short* __restrict__ dbf,
    const float* __restrict__ W0, short* __restrict__ w0h,
    short* __restrict__ w0l,
    const int* __restrict__ toks, const float* __restrict__ emb,
    short* __restrict__ xemb,
    short* __restrict__ hbuf, unsigned* __restrict__ bar)
{
    const int b = blockIdx.x, tid = threadIdx.x;
    if (b < 16000) {
        int id = b * 256 + tid;
        int e = id * 4;
        float4 v = *(const float4*)(dw + e);
        s4v o; o[0] = f2bf(v.x); o[1] = f2bf(v.y); o[2] = f2bf(v.z); o[3] = f2bf(v.w);
        *(s4v*)(dbf + e) = o;
    } else if (b < 20096) {
        int id = (b - 16000) * 256 + tid;      // < 2048*512
        float v = W0[id];
        short h = f2bf(v);
        w0h[id] = h;
        w0l[id] = f2bf(v - bf2f(h));
    } else if (b < 22144) {
        int id = (b - 20096) * 256 + tid;      // x4 elems over 4096*512
        int e  = id * 4;
        int tb = e >> 9;
        int k4 = e & 511;
        int tok = toks[tb];
        float4 v = *(const float4*)(emb + (size_t)tok * DIM + k4);
        s4v o; o[0] = f2bf(v.x); o[1] = f2bf(v.y); o[2] = f2bf(v.z); o[3] = f2bf(v.w);
        *(s4v*)(xemb + e) = o;
    } else {
        int id = (b - 22144) * 256 + tid;      // u64 index
        const int ringU64 = 129 * SLOT / 4;
        if (id < 2 * ringU64) {
            int r = id % ringU64;
            u64 v = (r < SLOT / 4) ? 0ull : 0xFFFFFFFFFFFFFFFFull;
            ((u64*)hbuf)[id] = v;
        }
        if (id < 64) bar[id] = 0;
    }
}

// ---------------- Gx0 GEMM: [4096,2048] = xemb @ (W0hi+W0lo)^T, fp32 out ----
__global__ __launch_bounds__(256) void gx_gemm(
    const short* __restrict__ A,
    const short* __restrict__ Bh,
    const short* __restrict__ Bl,
    float* __restrict__ out)
{
    const int nb = blockIdx.x & 15, mb = blockIdx.x >> 4;
    const int m0 = mb * 128, n0 = nb * 128;
    __shared__ short Alds[128][40];
    __shared__ short Bhl[128][40];
    __shared__ short Bll[128][40];
    const int tid = threadIdx.x, l = tid & 63, w = tid >> 6;
    const int wr = w >> 1, wc = w & 1;
    const int lr = l & 15, kg = l >> 4;

    f4v acc[4][4];
    #pragma unroll
    for (int mi = 0; mi < 4; ++mi)
        #pragma unroll
        for (int ni = 0; ni < 4; ++ni) {
            acc[mi][ni][0] = 0.f; acc[mi][ni][1] = 0.f;
            acc[mi][ni][2] = 0.f; acc[mi][ni][3] = 0.f;
        }

    for (int kt = 0; kt < 16; ++kt) {
        #pragma unroll
        for (int i = 0; i < 2; ++i) {
            int c = tid + i * 256;
            int row = c >> 2, q = (c & 3) << 3;
            *(s8v*)&Alds[row][q] = *(const s8v*)(A  + (size_t)(m0 + row) * 512 + kt * 32 + q);
            *(s8v*)&Bhl[row][q]  = *(const s8v*)(Bh + (size_t)(n0 + row) * 512 + kt * 32 + q);
            *(s8v*)&Bll[row][q]  = *(const s8v*)(Bl + (size_t)(n0 + row) * 512 + kt * 32 + q);
        }
        __syncthreads();
        s8v af[4], bhf[4], blf[4];
        #pragma unroll
        for (int i = 0; i < 4; ++i) {
            af[i]  = *(const s8v*)&Alds[wr * 64 + i * 16 + lr][kg * 8];
            bhf[i] = *(const s8v*)&Bhl[wc * 64 + i * 16 + lr][kg * 8];
            blf[i] = *(const s8v*)&Bll[wc * 64 + i * 16 + lr][kg * 8];
        }
        #pragma unroll
        for (int mi = 0; mi < 4; ++mi)
            #pragma unroll
            for (int ni = 0; ni < 4; ++ni) {
                acc[mi][ni] = mf16(af[mi], bhf[ni], acc[mi][ni]);
                acc[mi][ni] = mf16(af[mi], blf[ni], acc[mi][ni]);
            }
        __syncthreads();
    }

    #pragma unroll
    for (int mi = 0; mi < 4; ++mi)
        #pragma unroll
        for (int ni = 0; ni < 4; ++ni) {
            int n = n0 + wc * 64 + ni * 16 + lr;
            #pragma unroll
            for (int r = 0; r < 4; ++r) {
                int m = m0 + wr * 64 + mi * 16 + kg * 4 + r;
                out[(size_t)m * 2048 + n] = acc[mi][ni][r];
            }
        }
}

// ---------------- fused persistent recurrence + decoder ---------------------
__global__ __launch_bounds__(512, 1) void rnn_k(
    const float* __restrict__ W1f, const float* __restrict__ U0f,
    const float* __restrict__ U1f,
    const float* __restrict__ bias,
    const float* __restrict__ Gx,   // [4096][2048] fp32
    short* __restrict__ hbuf,       // ring0[129][SLOT] then ring1[129][SLOT]
    short* __restrict__ adec,       // [4096][512] bf16 (write-through)
    const short* __restrict__ dbf,  // dec_w bf16 [32000][512]
    const float* __restrict__ db,   // dec bias [32000]
    float* __restrict__ out,        // [4096][32000]
    unsigned* __restrict__ bar)     // flags1[32..63] (decoder gating only)
{
    const int tid = threadIdx.x;
    const int bx  = blockIdx.x;
    const int w2  = tid >> 6;
    const int l   = tid & 63;
    const int lr  = l & 15;
    const int kg  = l >> 4;

    __shared__ short Alds[32][520];
    __shared__ float gbuf[2][4][16][33];
    __shared__ float pbuf[2][4][16][33];
    __shared__ s8v AdT[4][132];
    __shared__ s8v BdT[4][132];

    if (bx >= NB) {
        // ================= decoder role =================
        const int d  = bx - NB;
        const int wm = w2 >> 2;
        const int wn = w2 & 3;
        const int drow = tid >> 2, dq = tid & 3;
        int lastmb = -1;
        for (int tile = d; tile < NTILE; tile += NDEC) {
            const int mb = tile / 250, nbt = tile - mb * 250;
            const int m0 = mb * 128, n0 = nbt * 128;
            if (mb != lastmb) {
                if (w2 == 0) poll32s(bar + 32, l, (unsigned)(4 * mb + 5));
                __syncthreads();
                lastmb = mb;
            }
            f4v acc[4][2];
            #pragma unroll
            for (int mi = 0; mi < 4; ++mi)
                #pragma unroll
                for (int ni = 0; ni < 2; ++ni) {
                    acc[mi][ni][0] = 0.f; acc[mi][ni][1] = 0.f;
                    acc[mi][ni][2] = 0.f; acc[mi][ni][3] = 0.f;
                }
            for (int kt = 0; kt < 16; ++kt) {
                AdT[dq][drow] = *(const s8v*)(adec + (size_t)(m0 + drow) * 512 + kt * 32 + dq * 8);
                BdT[dq][drow] = *(const s8v*)(dbf  + (size_t)(n0 + drow) * 512 + kt * 32 + dq * 8);
                __syncthreads();
                s8v af[4], bfr[2];
                #pragma unroll
                for (int i = 0; i < 4; ++i)
                    af[i] = AdT[kg][wm * 64 + i * 16 + lr];
                #pragma unroll
                for (int j = 0; j < 2; ++j)
                    bfr[j] = BdT[kg][wn * 32 + j * 16 + lr];
                #pragma unroll
                for (int mi = 0; mi < 4; ++mi)
                    #pragma unroll
                    for (int ni = 0; ni < 2; ++ni)
                        acc[mi][ni] = mf16(af[mi], bfr[ni], acc[mi][ni]);
                __syncthreads();
            }
            #pragma unroll
            for (int mi = 0; mi < 4; ++mi)
                #pragma unroll
                for (int ni = 0; ni < 2; ++ni) {
                    int n = n0 + wn * 32 + ni * 16 + lr;
                    float bb = db[n];
                    #pragma unroll
                    for (int r = 0; r < 4; ++r) {
                        int m = m0 + wm * 64 + mi * 16 + kg * 4 + r;
                        out[(size_t)m * NVOC + n] = acc[mi][ni][r] + bb;
                    }
                }
        }
        return;
    }

    // ================= recurrence roles =================
    const int bl    = bx;
    const int layer = bl >> 5;
    const int j0    = (bl & 31) * 16;

    // epilogue: 256 active threads, each 2 adjacent j -> packed 4B stores
    const bool epi = (tid < 256);
    const int eb  = (tid >> 3) & 31;          // batch 0..31
    const int ej  = (tid & 7) * 2;            // j: 0,2,..,14
    const int jg0 = j0 + ej;
    float bi0 = 0, bi1 = 0, bff0 = 0, bff1 = 0, bg0 = 0, bg1 = 0, bo0 = 0, bo1 = 0;
    if (epi) {
        bi0 = bias[jg0];         bi1 = bias[jg0 + 1];
        bff0 = bias[512 + jg0];  bff1 = bias[512 + jg0 + 1];
        bg0 = bias[1024 + jg0];  bg1 = bias[1024 + jg0 + 1];
        bo0 = bias[1536 + jg0];  bo1 = bias[1536 + jg0 + 1];
    }
    float c0 = 0.f, c1 = 0.f;

    short* ring0 = hbuf;                      // [129][SLOT]: slot t+1 = h0(t)
    short* ring1 = hbuf + 129 * SLOT;         // [129][SLOT]: slot t+1 = h1(t)

    // sentinel-polled stage: 32x512 bf16 slot -> Alds
    auto stageS = [&](const short* s) {
        u64 va[8];
        #pragma unroll
        for (int i = 0; i < 8; ++i) {
            int c = tid + i * 512;
            va[i] = cohload8(s + (c >> 7) * HID + (c & 127) * 4);
        }
        #pragma unroll
        for (int i = 0; i < 8; ++i) {
            int c = tid + i * 512;
            while (hasSent(va[i]))
                va[i] = cohload8(s + (c >> 7) * HID + (c & 127) * 4);
            *(u64*)&Alds[c >> 7][(c & 127) * 4] = va[i];
        }
    };
    const int g  = w2 & 3;
    const int kh = w2 >> 2;
    auto mfma8 = [&](const s8v* WH, const s8v* WL, float (&dst)[2][4][16][33]) {
        f4v a0h = {0.f, 0.f, 0.f, 0.f};
        f4v a0l = a0h, a1h = a0h, a1l = a0h;
        #pragma unroll
        for (int ks = 0; ks < 8; ++ks) {
            const int k = kh * 256 + ks * 32 + kg * 8;
            s8v a0 = *(const s8v*)&Alds[lr][k];
            s8v a1 = *(const s8v*)&Alds[16 + lr][k];
            a0h = mf16(a0, WH[ks], a0h);
            a0l = mf16(a0, WL[ks], a0l);
            a1h = mf16(a1, WH[ks], a1h);
            a1l = mf16(a1, WL[ks], a1l);
        }
        #pragma unroll
        for (int r = 0; r < 4; ++r) {
            dst[kh][g][lr][kg * 4 + r]      = a0h[r] + a0l[r];
            dst[kh][g][lr][16 + kg * 4 + r] = a1h[r] + a1l[r];
        }
    };
    const int gr = g * 512 + j0 + lr;
    auto loadw = [&](const float* M, s8v* WH, s8v* WL) {
        #pragma unroll
        for (int ks = 0; ks < 8; ++ks) {
            const float* src = M + (size_t)gr * 512 + kh * 256 + ks * 32 + kg * 8;
            float4 va = *(const float4*)src;
            float4 vb = *(const float4*)(src + 4);
            float vv[8] = {va.x, va.y, va.z, va.w, vb.x, vb.y, vb.z, vb.w};
            s8v hi, lo;
            #pragma unroll
            for (int e = 0; e < 8; ++e) {
                short h = f2bf(vv[e]);
                hi[e] = h; lo[e] = f2bf(vv[e] - bf2f(h));
            }
            WH[ks] = hi; WL[ks] = lo;
        }
    };

    if (layer == 0) {
        // ------- L0: h0(t) = act(U0·h0(t-1) + Gx(t)); no flags at all -------
        s8v wh[8], wl[8];
        loadw(U0f, wh, wl);
        for (int it = 0; it < SEQ; ++it) {
            float2 gxv0 = {0, 0}, gxv1 = {0, 0}, gxv2 = {0, 0}, gxv3 = {0, 0};
            if (epi) {
                const float* gp = Gx + ((size_t)it * BAT + eb) * 2048 + jg0;
                gxv0 = *(const float2*)(gp);
                gxv1 = *(const float2*)(gp + 512);
                gxv2 = *(const float2*)(gp + 1024);
                gxv3 = *(const float2*)(gp + 1536);
            }
            stageS(ring0 + (size_t)it * SLOT);         // h0(it-1)
            __syncthreads();
            mfma8(wh, wl, gbuf);
            __syncthreads();
            if (epi) {
                float si0 = gbuf[0][0][ej][eb]     + gbuf[1][0][ej][eb]     + gxv0.x;
                float si1 = gbuf[0][0][ej + 1][eb] + gbuf[1][0][ej + 1][eb] + gxv0.y;
                float sf0 = gbuf[0][1][ej][eb]     + gbuf[1][1][ej][eb]     + gxv1.x;
                float sf1 = gbuf[0][1][ej + 1][eb] + gbuf[1][1][ej + 1][eb] + gxv1.y;
                float sg0 = gbuf[0][2][ej][eb]     + gbuf[1][2][ej][eb]     + gxv2.x;
                float sg1 = gbuf[0][2][ej + 1][eb] + gbuf[1][2][ej + 1][eb] + gxv2.y;
                float so0 = gbuf[0][3][ej][eb]     + gbuf[1][3][ej][eb]     + gxv3.x;
                float so1 = gbuf[0][3][ej + 1][eb] + gbuf[1][3][ej + 1][eb] + gxv3.y;
                float gi0 = sigm(si0 + bi0), gi1 = sigm(si1 + bi1);
                float gf0 = sigm(sf0 + bff0), gf1 = sigm(sf1 + bff1);
                float gg0 = ftanh(sg0 + bg0), gg1 = ftanh(sg1 + bg1);
                float go0 = sigm(so0 + bo0), go1 = sigm(so1 + bo1);
                c0 = gf0 * c0 + gi0 * gg0;
                c1 = gf1 * c1 + gi1 * gg1;
                unsigned hw = (unsigned)(unsigned short)f2bf(go0 * ftanh(c0)) |
                              ((unsigned)(unsigned short)f2bf(go1 * ftanh(c1)) << 16);
                cohstore4(ring0 + (size_t)(it + 1) * SLOT + eb * HID + jg0, hw);
            }
        }
    } else {
        // -- L1 (pipelined): h1(t) = act(U1·h1(t-1) + pbuf:W1·h0(t)) ---------
        s8v whU[8], wlU[8], whW[8], wlW[8];
        loadw(U1f, whU, wlU);
        loadw(W1f, whW, wlW);
        // prologue: pbuf = W1·h0(0)
        stageS(ring0 + 1 * SLOT);
        __syncthreads();
        mfma8(whW, wlW, pbuf);
        __syncthreads();                       // Alds WAR guard (r13 race fix)
        for (int it = 1; it <= SEQ; ++it) {
            // pacing: compute h1(it-1) = act(U1·h1(it-2) + pbuf)
            stageS(ring1 + (size_t)(it - 1) * SLOT);   // h1(it-2)
            __syncthreads();
            mfma8(whU, wlU, gbuf);
            __syncthreads();
            unsigned hw = 0;
            if (epi) {
                float si0 = gbuf[0][0][ej][eb]     + gbuf[1][0][ej][eb]
                          + pbuf[0][0][ej][eb]     + pbuf[1][0][ej][eb];
                float si1 = gbuf[0][0][ej + 1][eb] + gbuf[1][0][ej + 1][eb]
                          + pbuf[0][0][ej + 1][eb] + pbuf[1][0][ej + 1][eb];
                float sf0 = gbuf[0][1][ej][eb]     + gbuf[1][1][ej][eb]
                          + pbuf[0][1][ej][eb]     + pbuf[1][1][ej][eb];
                float sf1 = gbuf[0][1][ej + 1][eb] + gbuf[1][1][ej + 1][eb]
                          + pbuf[0][1][ej + 1][eb] + pbuf[1][1][ej + 1][eb];
                float sg0 = gbuf[0][2][ej][eb]     + gbuf[1][2][ej][eb]
                          + pbuf[0][2][ej][eb]     + pbuf[1][2][ej][eb];
                float sg1 = gbuf[0][2][ej + 1][eb] + gbuf[1][2][ej + 1][eb]
                          + pbuf[0][2][ej + 1][eb] + pbuf[1][2][ej + 1][eb];
                float so0 = gbuf[0][3][ej][eb]     + gbuf[1][3][ej][eb]
                          + pbuf[0][3][ej][eb]     + pbuf[1][3][ej][eb];
                float so1 = gbuf[0][3][ej + 1][eb] + gbuf[1][3][ej + 1][eb]
                          + pbuf[0][3][ej + 1][eb] + pbuf[1][3][ej + 1][eb];
                float gi0 = sigm(si0 + bi0), gi1 = sigm(si1 + bi1);
                float gf0 = sigm(sf0 + bff0), gf1 = sigm(sf1 + bff1);
                float gg0 = ftanh(sg0 + bg0), gg1 = ftanh(sg1 + bg1);
                float go0 = sigm(so0 + bo0), go1 = sigm(so1 + bo1);
                c0 = gf0 * c0 + gi0 * gg0;
                c1 = gf1 * c1 + gi1 * gg1;
                hw = (unsigned)(unsigned short)f2bf(go0 * ftanh(c0)) |
                     ((unsigned)(unsigned short)f2bf(go1 * ftanh(c1)) << 16);
                cohstore4(ring1 + (size_t)it * SLOT + eb * HID + jg0, hw);
                cohstore4(adec + ((size_t)(it - 1) * BAT + eb) * HID + jg0, hw);
            }
            // decoder gating flag, every 4th step (off the h-chain)
            if ((it & 3) == 0 || it == SEQ) {
                asm volatile("s_waitcnt vmcnt(0)" ::: "memory");
                __syncthreads();
                if (tid == 0)
                    __hip_atomic_store(bar + 32 + (bl & 31), (unsigned)(it + 1),
                                       __ATOMIC_RELAXED, __HIP_MEMORY_SCOPE_AGENT);
            }
            // tail (slack): pbuf = W1·h0(it) for next iteration
            if (it < SEQ) {
                stageS(ring0 + (size_t)(it + 1) * SLOT);   // h0(it)
                __syncthreads();
                mfma8(whW, wlW, pbuf);
                __syncthreads();               // Alds WAR guard (r13 race fix)
            }
        }
    }
}

extern "C" void kernel_launch(void* const* d_in, const int* in_sizes, int n_in,
                              void* d_out, int out_size, void* d_ws, size_t ws_size,
                              hipStream_t stream)
{
    const int*   toks = (const int*)d_in[0];
    const float* emb  = (const float*)d_in[1];
    const float* W0   = (const float*)d_in[2];
    const float* W1   = (const float*)d_in[3];
    const float* U0   = (const float*)d_in[4];
    const float* U1   = (const float*)d_in[5];
    const float* bias = (const float*)d_in[6];
    const float* dw   = (const float*)d_in[7];
    const float* db   = (const float*)d_in[8];
    float* out = (float*)d_out;

    char* ws = (char*)d_ws;
    size_t off = 0;
    auto alloc = [&](size_t bytes) -> void* {
        void* p = ws + off;
        off += (bytes + 255) & ~(size_t)255;
        return p;
    };
    short*    dbf  = (short*)alloc((size_t)NVOC * DIM * 2);
    short*    xemb = (short*)alloc((size_t)SEQ * BAT * DIM * 2);
    short*    w0h  = (short*)alloc(2048ull * 512 * 2);
    short*    w0l  = (short*)alloc(2048ull * 512 * 2);
    float*    Gx   = (float*)alloc((size_t)SEQ * BAT * 2048 * 4);
    short*    hbuf = (short*)alloc(2ull * 129 * SLOT * 2);
    short*    adec = (short*)alloc((size_t)SEQ * BAT * HID * 2);
    unsigned* bar  = (unsigned*)alloc(256);

    prep_all<<<26272, 256, 0, stream>>>(dw, dbf, W0, w0h, w0l,
                                        toks, emb, xemb, hbuf, bar);

    gx_gemm<<<32 * 16, 256, 0, stream>>>(xemb, w0h, w0l, Gx);

    rnn_k<<<NB + NDEC, 512, 0, stream>>>(W1, U0, U1, bias, Gx, hbuf, adec,
                                         dbf, db, out, bar);
}

// Round 19
// 694.598 us; speedup vs baseline: 1.4986x; 1.0014x over previous
//
#include <hip/hip_runtime.h>
#include <hip/hip_bf16.h>

// ---------------------------------------------------------------------------
// LSTM LM forward on MI355X — round 19 (= round 17, the verified optimum).
// Fused persistent kernel (256 blocks x 512 thr): 32 L0 + 32 L1 + 192 decoder.
// Sentinel-polled write-once rings (129 slots) carry the h-chain (bf16 0xFFFF
// NaN sentinel); flags1 only gates the decoder (published every 4th step).
// L1 split into pacing phase (U1·h1 + epilogue) and tail (W1·h0 -> pbuf);
// the tail sits between the h1 store and the next h1 load, hiding the MALL
// round-trip. Packed 4B write-through h/adec stores; merged prep launch.
// ---------------------------------------------------------------------------

#define NVOC 32000
#define DIM  512
#define HID  512
#define SEQ  128
#define BAT  32
#define NB   64      // recurrence blocks (32 per layer)
#define NDEC 192     // decoder blocks
#define NTILE (32 * 250)
#define SLOT (BAT * HID)           // 16384 shorts per ring slot

typedef short s8v __attribute__((ext_vector_type(8)));
typedef short s4v __attribute__((ext_vector_type(4)));
typedef float f4v __attribute__((ext_vector_type(4)));
typedef unsigned long long u64;

__device__ __forceinline__ short f2bf(float f) {
    unsigned u = __builtin_bit_cast(unsigned, f);
    unsigned r = (u + 0x7fffu + ((u >> 16) & 1u)) >> 16;
    return (short)r;
}
__device__ __forceinline__ float bf2f(short s) {
    unsigned u = ((unsigned)(unsigned short)s) << 16;
    return __builtin_bit_cast(float, u);
}
__device__ __forceinline__ float sigm(float x) { return 1.f / (1.f + __expf(-x)); }
__device__ __forceinline__ float ftanh(float x) {
    float e = __expf(2.f * x);
    return 1.f - 2.f / (e + 1.f);
}

__device__ __forceinline__ f4v mf16(s8v a, s8v b, f4v c) {
    return __builtin_amdgcn_mfma_f32_16x16x32_bf16(a, b, c, 0, 0, 0);
}

// coherent (cross-XCD) loads/stores, bypassing L1+L2
__device__ __forceinline__ u64 cohload8(const short* p) {
    return __hip_atomic_load((const u64*)p, __ATOMIC_RELAXED,
                             __HIP_MEMORY_SCOPE_AGENT);
}
__device__ __forceinline__ void cohstore4(short* p, unsigned v) {
    __hip_atomic_store((unsigned*)p, v, __ATOMIC_RELAXED,
                       __HIP_MEMORY_SCOPE_AGENT);
}

// any halfword == 0xFFFF ? (has-zero-halfword test on ~v)
__device__ __forceinline__ bool hasSent(u64 v) {
    u64 n = ~v;
    return ((n - 0x0001000100010001ull) & ~n & 0x8000800080008000ull) != 0ull;
}

// 32-flag sleep-poll (decoder only)
__device__ __forceinline__ void poll32s(const unsigned* f, int l, unsigned tgt) {
    const unsigned* p = f + (l & 31);
    while (true) {
        unsigned v = __hip_atomic_load(p, __ATOMIC_RELAXED,
                                       __HIP_MEMORY_SCOPE_AGENT);
        if (__all((int)(v >= tgt))) break;
        __builtin_amdgcn_s_sleep(16);
    }
}

// ---------------- merged prep kernel ----------------------------------------
// blocks [0,16000): dec_w fp32->bf16 (NVOC*DIM/4 x4 elems)
// blocks [16000,20096): W0 split hi/lo (2048*512)
// blocks [20096,22144): embed gather -> xemb (SEQ*BAT*DIM/4 x4)
// blocks [22144,26272): ring init (sentinels) + flags
__global__ __launch_bounds__(256) void prep_all(
    const float* __restrict__ dw, short* __restrict__ dbf,
    const float* __restrict__ W0, short* __restrict__ w0h,
    short* __restrict__ w0l,
    const int* __restrict__ toks, const float* __restrict__ emb,
    short* __restrict__ xemb,
    short* __restrict__ hbuf, unsigned* __restrict__ bar)
{
    const int b = blockIdx.x, tid = threadIdx.x;
    if (b < 16000) {
        int id = b * 256 + tid;
        int e = id * 4;
        float4 v = *(const float4*)(dw + e);
        s4v o; o[0] = f2bf(v.x); o[1] = f2bf(v.y); o[2] = f2bf(v.z); o[3] = f2bf(v.w);
        *(s4v*)(dbf + e) = o;
    } else if (b < 20096) {
        int id = (b - 16000) * 256 + tid;      // < 2048*512
        float v = W0[id];
        short h = f2bf(v);
        w0h[id] = h;
        w0l[id] = f2bf(v - bf2f(h));
    } else if (b < 22144) {
        int id = (b - 20096) * 256 + tid;      // x4 elems over 4096*512
        int e  = id * 4;
        int tb = e >> 9;
        int k4 = e & 511;
        int tok = toks[tb];
        float4 v = *(const float4*)(emb + (size_t)tok * DIM + k4);
        s4v o; o[0] = f2bf(v.x); o[1] = f2bf(v.y); o[2] = f2bf(v.z); o[3] = f2bf(v.w);
        *(s4v*)(xemb + e) = o;
    } else {
        int id = (b - 22144) * 256 + tid;      // u64 index
        const int ringU64 = 129 * SLOT / 4;
        if (id < 2 * ringU64) {
            int r = id % ringU64;
            u64 v = (r < SLOT / 4) ? 0ull : 0xFFFFFFFFFFFFFFFFull;
            ((u64*)hbuf)[id] = v;
        }
        if (id < 64) bar[id] = 0;
    }
}

// ---------------- Gx0 GEMM: [4096,2048] = xemb @ (W0hi+W0lo)^T, fp32 out ----
__global__ __launch_bounds__(256) void gx_gemm(
    const short* __restrict__ A,
    const short* __restrict__ Bh,
    const short* __restrict__ Bl,
    float* __restrict__ out)
{
    const int nb = blockIdx.x & 15, mb = blockIdx.x >> 4;
    const int m0 = mb * 128, n0 = nb * 128;
    __shared__ short Alds[128][40];
    __shared__ short Bhl[128][40];
    __shared__ short Bll[128][40];
    const int tid = threadIdx.x, l = tid & 63, w = tid >> 6;
    const int wr = w >> 1, wc = w & 1;
    const int lr = l & 15, kg = l >> 4;

    f4v acc[4][4];
    #pragma unroll
    for (int mi = 0; mi < 4; ++mi)
        #pragma unroll
        for (int ni = 0; ni < 4; ++ni) {
            acc[mi][ni][0] = 0.f; acc[mi][ni][1] = 0.f;
            acc[mi][ni][2] = 0.f; acc[mi][ni][3] = 0.f;
        }

    for (int kt = 0; kt < 16; ++kt) {
        #pragma unroll
        for (int i = 0; i < 2; ++i) {
            int c = tid + i * 256;
            int row = c >> 2, q = (c & 3) << 3;
            *(s8v*)&Alds[row][q] = *(const s8v*)(A  + (size_t)(m0 + row) * 512 + kt * 32 + q);
            *(s8v*)&Bhl[row][q]  = *(const s8v*)(Bh + (size_t)(n0 + row) * 512 + kt * 32 + q);
            *(s8v*)&Bll[row][q]  = *(const s8v*)(Bl + (size_t)(n0 + row) * 512 + kt * 32 + q);
        }
        __syncthreads();
        s8v af[4], bhf[4], blf[4];
        #pragma unroll
        for (int i = 0; i < 4; ++i) {
            af[i]  = *(const s8v*)&Alds[wr * 64 + i * 16 + lr][kg * 8];
            bhf[i] = *(const s8v*)&Bhl[wc * 64 + i * 16 + lr][kg * 8];
            blf[i] = *(const s8v*)&Bll[wc * 64 + i * 16 + lr][kg * 8];
        }
        #pragma unroll
        for (int mi = 0; mi < 4; ++mi)
            #pragma unroll
            for (int ni = 0; ni < 4; ++ni) {
                acc[mi][ni] = mf16(af[mi], bhf[ni], acc[mi][ni]);
                acc[mi][ni] = mf16(af[mi], blf[ni], acc[mi][ni]);
            }
        __syncthreads();
    }

    #pragma unroll
    for (int mi = 0; mi < 4; ++mi)
        #pragma unroll
        for (int ni = 0; ni < 4; ++ni) {
            int n = n0 + wc * 64 + ni * 16 + lr;
            #pragma unroll
            for (int r = 0; r < 4; ++r) {
                int m = m0 + wr * 64 + mi * 16 + kg * 4 + r;
                out[(size_t)m * 2048 + n] = acc[mi][ni][r];
            }
        }
}

// ---------------- fused persistent recurrence + decoder ---------------------
__global__ __launch_bounds__(512, 1) void rnn_k(
    const float* __restrict__ W1f, const float* __restrict__ U0f,
    const float* __restrict__ U1f,
    const float* __restrict__ bias,
    const float* __restrict__ Gx,   // [4096][2048] fp32
    short* __restrict__ hbuf,       // ring0[129][SLOT] then ring1[129][SLOT]
    short* __restrict__ adec,       // [4096][512] bf16 (write-through)
    const short* __restrict__ dbf,  // dec_w bf16 [32000][512]
    const float* __restrict__ db,   // dec bias [32000]
    float* __restrict__ out,        // [4096][32000]
    unsigned* __restrict__ bar)     // flags1[32..63] (decoder gating only)
{
    const int tid = threadIdx.x;
    const int bx  = blockIdx.x;
    const int w2  = tid >> 6;
    const int l   = tid & 63;
    const int lr  = l & 15;
    const int kg  = l >> 4;

    __shared__ short Alds[32][520];
    __shared__ float gbuf[2][4][16][33];
    __shared__ float pbuf[2][4][16][33];
    __shared__ s8v AdT[4][132];
    __shared__ s8v BdT[4][132];

    if (bx >= NB) {
        // ================= decoder role =================
        const int d  = bx - NB;
        const int wm = w2 >> 2;
        const int wn = w2 & 3;
        const int drow = tid >> 2, dq = tid & 3;
        int lastmb = -1;
        for (int tile = d; tile < NTILE; tile += NDEC) {
            const int mb = tile / 250, nbt = tile - mb * 250;
            const int m0 = mb * 128, n0 = nbt * 128;
            if (mb != lastmb) {
                if (w2 == 0) poll32s(bar + 32, l, (unsigned)(4 * mb + 5));
                __syncthreads();
                lastmb = mb;
            }
            f4v acc[4][2];
            #pragma unroll
            for (int mi = 0; mi < 4; ++mi)
                #pragma unroll
                for (int ni = 0; ni < 2; ++ni) {
                    acc[mi][ni][0] = 0.f; acc[mi][ni][1] = 0.f;
                    acc[mi][ni][2] = 0.f; acc[mi][ni][3] = 0.f;
                }
            for (int kt = 0; kt < 16; ++kt) {
                AdT[dq][drow] = *(const s8v*)(adec + (size_t)(m0 + drow) * 512 + kt * 32 + dq * 8);
                BdT[dq][drow] = *(const s8v*)(dbf  + (size_t)(n0 + drow) * 512 + kt * 32 + dq * 8);
                __syncthreads();
                s8v af[4], bfr[2];
                #pragma unroll
                for (int i = 0; i < 4; ++i)
                    af[i] = AdT[kg][wm * 64 + i * 16 + lr];
                #pragma unroll
                for (int j = 0; j < 2; ++j)
                    bfr[j] = BdT[kg][wn * 32 + j * 16 + lr];
                #pragma unroll
                for (int mi = 0; mi < 4; ++mi)
                    #pragma unroll
                    for (int ni = 0; ni < 2; ++ni)
                        acc[mi][ni] = mf16(af[mi], bfr[ni], acc[mi][ni]);
                __syncthreads();
            }
            #pragma unroll
            for (int mi = 0; mi < 4; ++mi)
                #pragma unroll
                for (int ni = 0; ni < 2; ++ni) {
                    int n = n0 + wn * 32 + ni * 16 + lr;
                    float bb = db[n];
                    #pragma unroll
                    for (int r = 0; r < 4; ++r) {
                        int m = m0 + wm * 64 + mi * 16 + kg * 4 + r;
                        out[(size_t)m * NVOC + n] = acc[mi][ni][r] + bb;
                    }
                }
        }
        return;
    }

    // ================= recurrence roles =================
    const int bl    = bx;
    const int layer = bl >> 5;
    const int j0    = (bl & 31) * 16;

    // epilogue: 256 active threads, each 2 adjacent j -> packed 4B stores
    const bool epi = (tid < 256);
    const int eb  = (tid >> 3) & 31;          // batch 0..31
    const int ej  = (tid & 7) * 2;            // j: 0,2,..,14
    const int jg0 = j0 + ej;
    float bi0 = 0, bi1 = 0, bff0 = 0, bff1 = 0, bg0 = 0, bg1 = 0, bo0 = 0, bo1 = 0;
    if (epi) {
        bi0 = bias[jg0];         bi1 = bias[jg0 + 1];
        bff0 = bias[512 + jg0];  bff1 = bias[512 + jg0 + 1];
        bg0 = bias[1024 + jg0];  bg1 = bias[1024 + jg0 + 1];
        bo0 = bias[1536 + jg0];  bo1 = bias[1536 + jg0 + 1];
    }
    float c0 = 0.f, c1 = 0.f;

    short* ring0 = hbuf;                      // [129][SLOT]: slot t+1 = h0(t)
    short* ring1 = hbuf + 129 * SLOT;         // [129][SLOT]: slot t+1 = h1(t)

    // sentinel-polled stage: 32x512 bf16 slot -> Alds
    auto stageS = [&](const short* s) {
        u64 va[8];
        #pragma unroll
        for (int i = 0; i < 8; ++i) {
            int c = tid + i * 512;
            va[i] = cohload8(s + (c >> 7) * HID + (c & 127) * 4);
        }
        #pragma unroll
        for (int i = 0; i < 8; ++i) {
            int c = tid + i * 512;
            while (hasSent(va[i]))
                va[i] = cohload8(s + (c >> 7) * HID + (c & 127) * 4);
            *(u64*)&Alds[c >> 7][(c & 127) * 4] = va[i];
        }
    };
    const int g  = w2 & 3;
    const int kh = w2 >> 2;
    auto mfma8 = [&](const s8v* WH, const s8v* WL, float (&dst)[2][4][16][33]) {
        f4v a0h = {0.f, 0.f, 0.f, 0.f};
        f4v a0l = a0h, a1h = a0h, a1l = a0h;
        #pragma unroll
        for (int ks = 0; ks < 8; ++ks) {
            const int k = kh * 256 + ks * 32 + kg * 8;
            s8v a0 = *(const s8v*)&Alds[lr][k];
            s8v a1 = *(const s8v*)&Alds[16 + lr][k];
            a0h = mf16(a0, WH[ks], a0h);
            a0l = mf16(a0, WL[ks], a0l);
            a1h = mf16(a1, WH[ks], a1h);
            a1l = mf16(a1, WL[ks], a1l);
        }
        #pragma unroll
        for (int r = 0; r < 4; ++r) {
            dst[kh][g][lr][kg * 4 + r]      = a0h[r] + a0l[r];
            dst[kh][g][lr][16 + kg * 4 + r] = a1h[r] + a1l[r];
        }
    };
    const int gr = g * 512 + j0 + lr;
    auto loadw = [&](const float* M, s8v* WH, s8v* WL) {
        #pragma unroll
        for (int ks = 0; ks < 8; ++ks) {
            const float* src = M + (size_t)gr * 512 + kh * 256 + ks * 32 + kg * 8;
            float4 va = *(const float4*)src;
            float4 vb = *(const float4*)(src + 4);
            float vv[8] = {va.x, va.y, va.z, va.w, vb.x, vb.y, vb.z, vb.w};
            s8v hi, lo;
            #pragma unroll
            for (int e = 0; e < 8; ++e) {
                short h = f2bf(vv[e]);
                hi[e] = h; lo[e] = f2bf(vv[e] - bf2f(h));
            }
            WH[ks] = hi; WL[ks] = lo;
        }
    };

    if (layer == 0) {
        // ------- L0: h0(t) = act(U0·h0(t-1) + Gx(t)); no flags at all -------
        s8v wh[8], wl[8];
        loadw(U0f, wh, wl);
        for (int it = 0; it < SEQ; ++it) {
            float2 gxv0 = {0, 0}, gxv1 = {0, 0}, gxv2 = {0, 0}, gxv3 = {0, 0};
            if (epi) {
                const float* gp = Gx + ((size_t)it * BAT + eb) * 2048 + jg0;
                gxv0 = *(const float2*)(gp);
                gxv1 = *(const float2*)(gp + 512);
                gxv2 = *(const float2*)(gp + 1024);
                gxv3 = *(const float2*)(gp + 1536);
            }
            stageS(ring0 + (size_t)it * SLOT);         // h0(it-1)
            __syncthreads();
            mfma8(wh, wl, gbuf);
            __syncthreads();
            if (epi) {
                float si0 = gbuf[0][0][ej][eb]     + gbuf[1][0][ej][eb]     + gxv0.x;
                float si1 = gbuf[0][0][ej + 1][eb] + gbuf[1][0][ej + 1][eb] + gxv0.y;
                float sf0 = gbuf[0][1][ej][eb]     + gbuf[1][1][ej][eb]     + gxv1.x;
                float sf1 = gbuf[0][1][ej + 1][eb] + gbuf[1][1][ej + 1][eb] + gxv1.y;
                float sg0 = gbuf[0][2][ej][eb]     + gbuf[1][2][ej][eb]     + gxv2.x;
                float sg1 = gbuf[0][2][ej + 1][eb] + gbuf[1][2][ej + 1][eb] + gxv2.y;
                float so0 = gbuf[0][3][ej][eb]     + gbuf[1][3][ej][eb]     + gxv3.x;
                float so1 = gbuf[0][3][ej + 1][eb] + gbuf[1][3][ej + 1][eb] + gxv3.y;
                float gi0 = sigm(si0 + bi0), gi1 = sigm(si1 + bi1);
                float gf0 = sigm(sf0 + bff0), gf1 = sigm(sf1 + bff1);
                float gg0 = ftanh(sg0 + bg0), gg1 = ftanh(sg1 + bg1);
                float go0 = sigm(so0 + bo0), go1 = sigm(so1 + bo1);
                c0 = gf0 * c0 + gi0 * gg0;
                c1 = gf1 * c1 + gi1 * gg1;
                unsigned hw = (unsigned)(unsigned short)f2bf(go0 * ftanh(c0)) |
                              ((unsigned)(unsigned short)f2bf(go1 * ftanh(c1)) << 16);
                cohstore4(ring0 + (size_t)(it + 1) * SLOT + eb * HID + jg0, hw);
            }
        }
    } else {
        // -- L1 (pipelined): h1(t) = act(U1·h1(t-1) + pbuf:W1·h0(t)) ---------
        s8v whU[8], wlU[8], whW[8], wlW[8];
        loadw(U1f, whU, wlU);
        loadw(W1f, whW, wlW);
        // prologue: pbuf = W1·h0(0)
        stageS(ring0 + 1 * SLOT);
        __syncthreads();
        mfma8(whW, wlW, pbuf);
        __syncthreads();                       // Alds WAR guard
        for (int it = 1; it <= SEQ; ++it) {
            // pacing: compute h1(it-1) = act(U1·h1(it-2) + pbuf)
            stageS(ring1 + (size_t)(it - 1) * SLOT);   // h1(it-2)
            __syncthreads();
            mfma8(whU, wlU, gbuf);
            __syncthreads();
            unsigned hw = 0;
            if (epi) {
                float si0 = gbuf[0][0][ej][eb]     + gbuf[1][0][ej][eb]
                          + pbuf[0][0][ej][eb]     + pbuf[1][0][ej][eb];
                float si1 = gbuf[0][0][ej + 1][eb] + gbuf[1][0][ej + 1][eb]
                          + pbuf[0][0][ej + 1][eb] + pbuf[1][0][ej + 1][eb];
                float sf0 = gbuf[0][1][ej][eb]     + gbuf[1][1][ej][eb]
                          + pbuf[0][1][ej][eb]     + pbuf[1][1][ej][eb];
                float sf1 = gbuf[0][1][ej + 1][eb] + gbuf[1][1][ej + 1][eb]
                          + pbuf[0][1][ej + 1][eb] + pbuf[1][1][ej + 1][eb];
                float sg0 = gbuf[0][2][ej][eb]     + gbuf[1][2][ej][eb]
                          + pbuf[0][2][ej][eb]     + pbuf[1][2][ej][eb];
                float sg1 = gbuf[0][2][ej + 1][eb] + gbuf[1][2][ej + 1][eb]
                          + pbuf[0][2][ej + 1][eb] + pbuf[1][2][ej + 1][eb];
                float so0 = gbuf[0][3][ej][eb]     + gbuf[1][3][ej][eb]
                          + pbuf[0][3][ej][eb]     + pbuf[1][3][ej][eb];
                float so1 = gbuf[0][3][ej + 1][eb] + gbuf[1][3][ej + 1][eb]
                          + pbuf[0][3][ej + 1][eb] + pbuf[1][3][ej + 1][eb];
                float gi0 = sigm(si0 + bi0), gi1 = sigm(si1 + bi1);
                float gf0 = sigm(sf0 + bff0), gf1 = sigm(sf1 + bff1);
                float gg0 = ftanh(sg0 + bg0), gg1 = ftanh(sg1 + bg1);
                float go0 = sigm(so0 + bo0), go1 = sigm(so1 + bo1);
                c0 = gf0 * c0 + gi0 * gg0;
                c1 = gf1 * c1 + gi1 * gg1;
                hw = (unsigned)(unsigned short)f2bf(go0 * ftanh(c0)) |
                     ((unsigned)(unsigned short)f2bf(go1 * ftanh(c1)) << 16);
                cohstore4(ring1 + (size_t)it * SLOT + eb * HID + jg0, hw);
                cohstore4(adec + ((size_t)(it - 1) * BAT + eb) * HID + jg0, hw);
            }
            // decoder gating flag, every 4th step (off the h-chain)
            if ((it & 3) == 0 || it == SEQ) {
                asm volatile("s_waitcnt vmcnt(0)" ::: "memory");
                __syncthreads();
                if (tid == 0)
                    __hip_atomic_store(bar + 32 + (bl & 31), (unsigned)(it + 1),
                                       __ATOMIC_RELAXED, __HIP_MEMORY_SCOPE_AGENT);
            }
            // tail (slack): pbuf = W1·h0(it) for next iteration
            if (it < SEQ) {
                stageS(ring0 + (size_t)(it + 1) * SLOT);   // h0(it)
                __syncthreads();
                mfma8(whW, wlW, pbuf);
                __syncthreads();               // Alds WAR guard
            }
        }
    }
}

extern "C" void kernel_launch(void* const* d_in, const int* in_sizes, int n_in,
                              void* d_out, int out_size, void* d_ws, size_t ws_size,
                              hipStream_t stream)
{
    const int*   toks = (const int*)d_in[0];
    const float* emb  = (const float*)d_in[1];
    const float* W0   = (const float*)d_in[2];
    const float* W1   = (const float*)d_in[3];
    const float* U0   = (const float*)d_in[4];
    const float* U1   = (const float*)d_in[5];
    const float* bias = (const float*)d_in[6];
    const float* dw   = (const float*)d_in[7];
    const float* db   = (const float*)d_in[8];
    float* out = (float*)d_out;

    char* ws = (char*)d_ws;
    size_t off = 0;
    auto alloc = [&](size_t bytes) -> void* {
        void* p = ws + off;
        off += (bytes + 255) & ~(size_t)255;
        return p;
    };
    short*    dbf  = (short*)alloc((size_t)NVOC * DIM * 2);
    short*    xemb = (short*)alloc((size_t)SEQ * BAT * DIM * 2);
    short*    w0h  = (short*)alloc(2048ull * 512 * 2);
    short*    w0l  = (short*)alloc(2048ull * 512 * 2);
    float*    Gx   = (float*)alloc((size_t)SEQ * BAT * 2048 * 4);
    short*    hbuf = (short*)alloc(2ull * 129 * SLOT * 2);
    short*    adec = (short*)alloc((size_t)SEQ * BAT * HID * 2);
    unsigned* bar  = (unsigned*)alloc(256);

    prep_all<<<26272, 256, 0, stream>>>(dw, dbf, W0, w0h, w0l,
                                        toks, emb, xemb, hbuf, bar);

    gx_gemm<<<32 * 16, 256, 0, stream>>>(xemb, w0h, w0l, Gx);

    rnn_k<<<NB + NDEC, 512, 0, stream>>>(W1, U0, U1, bias, Gx, hbuf, adec,
                                         dbf, db, out, bar);
}